// Round 1
// baseline (69.844 us; speedup 1.0000x reference)
//
#include <hip/hip_runtime.h>
#include <stdint.h>

typedef short bf16x8 __attribute__((ext_vector_type(8)));
typedef float f32x16 __attribute__((ext_vector_type(16)));
typedef unsigned short ushort_t;

#define NTOK 16384   // 32*512
#define EMB 256
#define HID 1024

// ---------------- ws layout ----------------
// [0, 8MB)            : A_bf16 [16384][256]
// [8MB, 8MB+512KB)    : W_bf16 [1024][256]
// [8MB+512KB, +4)     : id-width flag (1 = int64, 0 = int32)
#define WS_A_OFF   0
#define WS_W_OFF   (8u * 1024u * 1024u)
#define WS_F_OFF   (WS_W_OFF + 512u * 1024u)

__device__ __forceinline__ uint32_t rotr32(uint32_t x, int n) {
    return (x >> n) | (x << (32 - n));
}

// Detect int32 vs int64 layout of input_ids. Reads only within the minimum
// guaranteed 64 KB (16384 * 4B). If the buffer is int64 little-endian, every
// odd 32-bit word (hi half of a nonneg value < 32000) is zero.
__global__ __launch_bounds__(256) void detect_kernel(const uint32_t* __restrict__ ids32,
                                                     uint32_t* __restrict__ flag) {
    __shared__ uint32_t red[256];
    uint32_t acc = 0;
    for (int i = threadIdx.x; i < 8192; i += 256) acc |= ids32[2 * i + 1];
    red[threadIdx.x] = acc;
    __syncthreads();
    if (threadIdx.x == 0) {
        uint32_t o = 0;
        for (int i = 0; i < 256; ++i) o |= red[i];
        *flag = (o == 0) ? 1u : 0u;
    }
}

// Per token: SHA-256 + SHA-224 first-digest-byte, then write the bf16 A-row.
__global__ __launch_bounds__(256) void hash_fill_kernel(const uint32_t* __restrict__ ids32,
                                                        const uint32_t* __restrict__ flag,
                                                        ushort_t* __restrict__ A) {
    const int t = blockIdx.x * 256 + threadIdx.x;
    if (t >= NTOK) return;
    const uint32_t is64 = *flag;
    const uint32_t v = is64 ? ids32[2 * t] : ids32[t];

    // Build the single padded block: decimal digits, 0x80, zeros, bitlen.
    const uint32_t nd = v >= 10000u ? 5u : v >= 1000u ? 4u : v >= 100u ? 3u
                         : v >= 10u ? 2u : 1u;
    uint64_t be = 0;  // bytes 0..7 of the message, byte 0 in bits [63:56]
    uint32_t tmp = v;
    for (int j = (int)nd - 1; j >= 0; --j) {
        be |= (uint64_t)('0' + (tmp % 10u)) << (56 - 8 * j);
        tmp /= 10u;
    }
    be |= (uint64_t)0x80u << (56 - 8 * (int)nd);

    uint32_t w[16];
    w[0] = (uint32_t)(be >> 32);
    w[1] = (uint32_t)be;
#pragma unroll
    for (int i = 2; i < 15; ++i) w[i] = 0;
    w[15] = nd * 8u;

    const uint32_t K[64] = {
        0x428a2f98u,0x71374491u,0xb5c0fbcfu,0xe9b5dba5u,0x3956c25bu,0x59f111f1u,0x923f82a4u,0xab1c5ed5u,
        0xd807aa98u,0x12835b01u,0x243185beu,0x550c7dc3u,0x72be5d74u,0x80deb1feu,0x9bdc06a7u,0xc19bf174u,
        0xe49b69c1u,0xefbe4786u,0x0fc19dc6u,0x240ca1ccu,0x2de92c6fu,0x4a7484aau,0x5cb0a9dcu,0x76f988dau,
        0x983e5152u,0xa831c66du,0xb00327c8u,0xbf597fc7u,0xc6e00bf3u,0xd5a79147u,0x06ca6351u,0x14292967u,
        0x27b70a85u,0x2e1b2138u,0x4d2c6dfcu,0x53380d13u,0x650a7354u,0x766a0abbu,0x81c2c92eu,0x92722c85u,
        0xa2bfe8a1u,0xa81a664bu,0xc24b8b70u,0xc76c51a3u,0xd192e819u,0xd6990624u,0xf40e3585u,0x106aa070u,
        0x19a4c116u,0x1e376c08u,0x2748774cu,0x34b0bcb5u,0x391c0cb3u,0x4ed8aa4au,0x5b9cca4fu,0x682e6ff3u,
        0x748f82eeu,0x78a5636fu,0x84c87814u,0x8cc70208u,0x90befffau,0xa4506cebu,0xbef9a3f7u,0xc67178f2u};

    // Two compression states (SHA-256 IV, SHA-224 IV), shared schedule.
    uint32_t a0=0x6a09e667u,b0=0xbb67ae85u,c0=0x3c6ef372u,d0=0xa54ff53au,
             e0=0x510e527fu,f0=0x9b05688cu,g0=0x1f83d9abu,h0=0x5be0cd19u;
    uint32_t a1=0xc1059ed8u,b1=0x367cd507u,c1=0x3070dd17u,d1=0xf70e5939u,
             e1=0xffc00b31u,f1=0x68581511u,g1=0x64f98fa7u,h1=0xbefa4fa4u;

#pragma unroll
    for (int tt = 0; tt < 64; ++tt) {
        uint32_t wt;
        if (tt < 16) {
            wt = w[tt];
        } else {
            uint32_t w2 = w[(tt - 2) & 15], w7 = w[(tt - 7) & 15];
            uint32_t w15 = w[(tt - 15) & 15], w16 = w[tt & 15];
            uint32_t s0 = rotr32(w15, 7) ^ rotr32(w15, 18) ^ (w15 >> 3);
            uint32_t s1 = rotr32(w2, 17) ^ rotr32(w2, 19) ^ (w2 >> 10);
            wt = w16 + s0 + w7 + s1;
            w[tt & 15] = wt;
        }
        const uint32_t kw = K[tt] + wt;
        {
            uint32_t S1 = rotr32(e0, 6) ^ rotr32(e0, 11) ^ rotr32(e0, 25);
            uint32_t ch = (e0 & f0) ^ (~e0 & g0);
            uint32_t T1 = h0 + S1 + ch + kw;
            uint32_t S0 = rotr32(a0, 2) ^ rotr32(a0, 13) ^ rotr32(a0, 22);
            uint32_t mj = (a0 & b0) ^ (a0 & c0) ^ (b0 & c0);
            uint32_t T2 = S0 + mj;
            h0 = g0; g0 = f0; f0 = e0; e0 = d0 + T1;
            d0 = c0; c0 = b0; b0 = a0; a0 = T1 + T2;
        }
        {
            uint32_t S1 = rotr32(e1, 6) ^ rotr32(e1, 11) ^ rotr32(e1, 25);
            uint32_t ch = (e1 & f1) ^ (~e1 & g1);
            uint32_t T1 = h1 + S1 + ch + kw;
            uint32_t S0 = rotr32(a1, 2) ^ rotr32(a1, 13) ^ rotr32(a1, 22);
            uint32_t mj = (a1 & b1) ^ (a1 & c1) ^ (b1 & c1);
            uint32_t T2 = S0 + mj;
            h1 = g1; g1 = f1; f1 = e1; e1 = d1 + T1;
            d1 = c1; c1 = b1; b1 = a1; a1 = T1 + T2;
        }
    }
    const uint32_t hv1 = ((0x6a09e667u + a0) >> 24) & 0xFFu;  // sha256 digest[0]
    const uint32_t hv2 = ((0xc1059ed8u + a1) >> 24) & 0xFFu;  // sha224 digest[0]

    // A[t][k] = bf16((hv1 + k*hv2) & 255)  — integers 0..255 are exact in bf16.
    ushort_t* row = A + (size_t)t * EMB;
#pragma unroll
    for (int k0 = 0; k0 < EMB; k0 += 8) {
        bf16x8 pack;
#pragma unroll
        for (int e = 0; e < 8; ++e) {
            uint32_t val = (hv1 + (uint32_t)(k0 + e) * hv2) & 255u;
            float ff = (float)val;
            pack[e] = (short)(__float_as_uint(ff) >> 16);  // exact truncation
        }
        *reinterpret_cast<bf16x8*>(row + k0) = pack;
    }
}

// W fp32 -> bf16 (RNE)
__global__ __launch_bounds__(256) void wconv_kernel(const float* __restrict__ W,
                                                    ushort_t* __restrict__ Wb) {
    const int i = blockIdx.x * 256 + threadIdx.x;  // 65536 threads * 4 floats
    float4 f = reinterpret_cast<const float4*>(W)[i];
    auto cvt = [](float x) -> ushort_t {
        uint32_t b = __float_as_uint(x);
        return (ushort_t)((b + 0x7FFFu + ((b >> 16) & 1u)) >> 16);
    };
    ushort4 o;
    o.x = cvt(f.x); o.y = cvt(f.y); o.z = cvt(f.z); o.w = cvt(f.w);
    reinterpret_cast<ushort4*>(Wb)[i] = o;
}

// GEMM: C[t][h] = sum_e A[t][e] * W[h][e] + b[h]
// B[k][n] = Wb[n*256 + k]  (contiguous in k -> 16B fragment loads)
// block = 4 waves (2x2), wave tile 64x64, block tile 128x128, no LDS.
__global__ __launch_bounds__(256) void gemm_kernel(const ushort_t* __restrict__ A,
                                                   const ushort_t* __restrict__ Wb,
                                                   const float* __restrict__ bias,
                                                   float* __restrict__ out) {
    const int bid = blockIdx.x;   // 1024 = 128(M) * 8(N)
    const int bn = bid & 7;
    const int bm = bid >> 3;
    const int tid = (int)threadIdx.x;
    const int wave = tid >> 6;
    const int lane = tid & 63;
    const int lrow = lane & 31;
    const int lh = lane >> 5;  // K-half group

    const int m0 = bm * 128 + (wave >> 1) * 64;
    const int n0 = bn * 128 + (wave & 1) * 64;

    const ushort_t* Ap = A + (size_t)(m0 + lrow) * EMB + lh * 8;
    const ushort_t* Bp = Wb + (size_t)(n0 + lrow) * EMB + lh * 8;

    f32x16 acc00 = {}, acc01 = {}, acc10 = {}, acc11 = {};
#pragma unroll 4
    for (int ks = 0; ks < 16; ++ks) {
        bf16x8 av0 = *reinterpret_cast<const bf16x8*>(Ap + ks * 16);
        bf16x8 av1 = *reinterpret_cast<const bf16x8*>(Ap + 32 * EMB + ks * 16);
        bf16x8 bv0 = *reinterpret_cast<const bf16x8*>(Bp + ks * 16);
        bf16x8 bv1 = *reinterpret_cast<const bf16x8*>(Bp + 32 * EMB + ks * 16);
        acc00 = __builtin_amdgcn_mfma_f32_32x32x16_bf16(av0, bv0, acc00, 0, 0, 0);
        acc01 = __builtin_amdgcn_mfma_f32_32x32x16_bf16(av0, bv1, acc01, 0, 0, 0);
        acc10 = __builtin_amdgcn_mfma_f32_32x32x16_bf16(av1, bv0, acc10, 0, 0, 0);
        acc11 = __builtin_amdgcn_mfma_f32_32x32x16_bf16(av1, bv1, acc11, 0, 0, 0);
    }

    const float bj0 = bias[n0 + lrow];
    const float bj1 = bias[n0 + 32 + lrow];
#pragma unroll
    for (int r = 0; r < 16; ++r) {
        const int rowl = (r & 3) + 8 * (r >> 2) + 4 * lh;  // verified C/D layout
        const size_t off0 = (size_t)(m0 + rowl) * HID;
        const size_t off1 = (size_t)(m0 + 32 + rowl) * HID;
        out[off0 + n0 + lrow]      = acc00[r] + bj0;
        out[off0 + n0 + 32 + lrow] = acc01[r] + bj1;
        out[off1 + n0 + lrow]      = acc10[r] + bj0;
        out[off1 + n0 + 32 + lrow] = acc11[r] + bj1;
    }
}

extern "C" void kernel_launch(void* const* d_in, const int* in_sizes, int n_in,
                              void* d_out, int out_size, void* d_ws, size_t ws_size,
                              hipStream_t stream) {
    const uint32_t* ids32 = (const uint32_t*)d_in[0];
    const float* W = (const float*)d_in[1];
    const float* bias = (const float*)d_in[2];
    float* out = (float*)d_out;

    ushort_t* A = (ushort_t*)((char*)d_ws + WS_A_OFF);
    ushort_t* Wb = (ushort_t*)((char*)d_ws + WS_W_OFF);
    uint32_t* flag = (uint32_t*)((char*)d_ws + WS_F_OFF);

    detect_kernel<<<1, 256, 0, stream>>>(ids32, flag);
    hash_fill_kernel<<<NTOK / 256, 256, 0, stream>>>(ids32, flag, A);
    wconv_kernel<<<(HID * EMB / 4) / 256, 256, 0, stream>>>(W, Wb);
    gemm_kernel<<<(NTOK / 128) * (HID / 128), 256, 0, stream>>>(A, Wb, bias, out);
}

// Round 2
// 47.796 us; speedup vs baseline: 1.4613x; 1.4613x over previous
//
#include <hip/hip_runtime.h>
#include <stdint.h>

typedef short bf16x8 __attribute__((ext_vector_type(8)));
typedef float f32x16 __attribute__((ext_vector_type(16)));
typedef unsigned short ushort_t;

#define NTOK 16384   // 32*512
#define EMB 256
#define HID 1024

// ---------------- ws layout ----------------
#define WS_A_OFF   0
#define WS_W_OFF   (8u * 1024u * 1024u)
#define WS_F_OFF   (WS_W_OFF + 512u * 1024u)

__device__ __forceinline__ uint32_t rotr32(uint32_t x, int n) {
    return (x >> n) | (x << (32 - n));
}

#define STAGE16(gsrc, ldsdst)                                                        \
    __builtin_amdgcn_global_load_lds(                                                \
        (const __attribute__((address_space(1))) void*)(gsrc),                       \
        (__attribute__((address_space(3))) void*)(ldsdst), 16, 0, 0)

// Detect int32 vs int64 layout of input_ids (odd 32-bit words all zero => int64).
__global__ __launch_bounds__(256) void detect_kernel(const uint32_t* __restrict__ ids32,
                                                     uint32_t* __restrict__ flag) {
    __shared__ uint32_t red[256];
    uint32_t acc = 0;
    for (int i = threadIdx.x; i < 8192; i += 256) acc |= ids32[2 * i + 1];
    red[threadIdx.x] = acc;
    __syncthreads();
    if (threadIdx.x == 0) {
        uint32_t o = 0;
        for (int i = 0; i < 256; ++i) o |= red[i];
        *flag = (o == 0) ? 1u : 0u;
    }
}

// Per token: SHA-256 + SHA-224 first-digest-byte, then write the bf16 A-row.
// 64 threads/block, 256 blocks -> one wave on every CU.
__global__ __launch_bounds__(64) void hash_fill_kernel(const uint32_t* __restrict__ ids32,
                                                       const uint32_t* __restrict__ flag,
                                                       ushort_t* __restrict__ A) {
    const int t = blockIdx.x * 64 + threadIdx.x;
    const uint32_t is64 = *flag;
    const uint32_t v = is64 ? ids32[2 * t] : ids32[t];

    const uint32_t nd = v >= 10000u ? 5u : v >= 1000u ? 4u : v >= 100u ? 3u
                         : v >= 10u ? 2u : 1u;
    uint64_t be = 0;
    uint32_t tmp = v;
    for (int j = (int)nd - 1; j >= 0; --j) {
        be |= (uint64_t)('0' + (tmp % 10u)) << (56 - 8 * j);
        tmp /= 10u;
    }
    be |= (uint64_t)0x80u << (56 - 8 * (int)nd);

    uint32_t w[16];
    w[0] = (uint32_t)(be >> 32);
    w[1] = (uint32_t)be;
#pragma unroll
    for (int i = 2; i < 15; ++i) w[i] = 0;
    w[15] = nd * 8u;

    const uint32_t K[64] = {
        0x428a2f98u,0x71374491u,0xb5c0fbcfu,0xe9b5dba5u,0x3956c25bu,0x59f111f1u,0x923f82a4u,0xab1c5ed5u,
        0xd807aa98u,0x12835b01u,0x243185beu,0x550c7dc3u,0x72be5d74u,0x80deb1feu,0x9bdc06a7u,0xc19bf174u,
        0xe49b69c1u,0xefbe4786u,0x0fc19dc6u,0x240ca1ccu,0x2de92c6fu,0x4a7484aau,0x5cb0a9dcu,0x76f988dau,
        0x983e5152u,0xa831c66du,0xb00327c8u,0xbf597fc7u,0xc6e00bf3u,0xd5a79147u,0x06ca6351u,0x14292967u,
        0x27b70a85u,0x2e1b2138u,0x4d2c6dfcu,0x53380d13u,0x650a7354u,0x766a0abbu,0x81c2c92eu,0x92722c85u,
        0xa2bfe8a1u,0xa81a664bu,0xc24b8b70u,0xc76c51a3u,0xd192e819u,0xd6990624u,0xf40e3585u,0x106aa070u,
        0x19a4c116u,0x1e376c08u,0x2748774cu,0x34b0bcb5u,0x391c0cb3u,0x4ed8aa4au,0x5b9cca4fu,0x682e6ff3u,
        0x748f82eeu,0x78a5636fu,0x84c87814u,0x8cc70208u,0x90befffau,0xa4506cebu,0xbef9a3f7u,0xc67178f2u};

    uint32_t a0=0x6a09e667u,b0=0xbb67ae85u,c0=0x3c6ef372u,d0=0xa54ff53au,
             e0=0x510e527fu,f0=0x9b05688cu,g0=0x1f83d9abu,h0=0x5be0cd19u;
    uint32_t a1=0xc1059ed8u,b1=0x367cd507u,c1=0x3070dd17u,d1=0xf70e5939u,
             e1=0xffc00b31u,f1=0x68581511u,g1=0x64f98fa7u,h1=0xbefa4fa4u;

#pragma unroll
    for (int tt = 0; tt < 64; ++tt) {
        uint32_t wt;
        if (tt < 16) {
            wt = w[tt];
        } else {
            uint32_t w2 = w[(tt - 2) & 15], w7 = w[(tt - 7) & 15];
            uint32_t w15 = w[(tt - 15) & 15], w16 = w[tt & 15];
            uint32_t s0 = rotr32(w15, 7) ^ rotr32(w15, 18) ^ (w15 >> 3);
            uint32_t s1 = rotr32(w2, 17) ^ rotr32(w2, 19) ^ (w2 >> 10);
            wt = w16 + s0 + w7 + s1;
            w[tt & 15] = wt;
        }
        const uint32_t kw = K[tt] + wt;
        {
            uint32_t S1 = rotr32(e0, 6) ^ rotr32(e0, 11) ^ rotr32(e0, 25);
            uint32_t ch = (e0 & f0) ^ (~e0 & g0);
            uint32_t T1 = h0 + S1 + ch + kw;
            uint32_t S0 = rotr32(a0, 2) ^ rotr32(a0, 13) ^ rotr32(a0, 22);
            uint32_t mj = (a0 & b0) ^ (a0 & c0) ^ (b0 & c0);
            uint32_t T2 = S0 + mj;
            h0 = g0; g0 = f0; f0 = e0; e0 = d0 + T1;
            d0 = c0; c0 = b0; b0 = a0; a0 = T1 + T2;
        }
        {
            uint32_t S1 = rotr32(e1, 6) ^ rotr32(e1, 11) ^ rotr32(e1, 25);
            uint32_t ch = (e1 & f1) ^ (~e1 & g1);
            uint32_t T1 = h1 + S1 + ch + kw;
            uint32_t S0 = rotr32(a1, 2) ^ rotr32(a1, 13) ^ rotr32(a1, 22);
            uint32_t mj = (a1 & b1) ^ (a1 & c1) ^ (b1 & c1);
            uint32_t T2 = S0 + mj;
            h1 = g1; g1 = f1; f1 = e1; e1 = d1 + T1;
            d1 = c1; c1 = b1; b1 = a1; a1 = T1 + T2;
        }
    }
    const uint32_t hv1 = ((0x6a09e667u + a0) >> 24) & 0xFFu;  // sha256 digest[0]
    const uint32_t hv2 = ((0xc1059ed8u + a1) >> 24) & 0xFFu;  // sha224 digest[0]

    ushort_t* row = A + (size_t)t * EMB;
#pragma unroll
    for (int k0 = 0; k0 < EMB; k0 += 8) {
        bf16x8 pack;
#pragma unroll
        for (int e = 0; e < 8; ++e) {
            uint32_t val = (hv1 + (uint32_t)(k0 + e) * hv2) & 255u;
            pack[e] = (short)(__float_as_uint((float)val) >> 16);  // exact
        }
        *reinterpret_cast<bf16x8*>(row + k0) = pack;
    }
}

// W fp32 -> bf16 (RNE)
__global__ __launch_bounds__(256) void wconv_kernel(const float* __restrict__ W,
                                                    ushort_t* __restrict__ Wb) {
    const int i = blockIdx.x * 256 + threadIdx.x;
    float4 f = reinterpret_cast<const float4*>(W)[i];
    auto cvt = [](float x) -> ushort_t {
        uint32_t b = __float_as_uint(x);
        return (ushort_t)((b + 0x7FFFu + ((b >> 16) & 1u)) >> 16);
    };
    ushort4 o;
    o.x = cvt(f.x); o.y = cvt(f.y); o.z = cvt(f.z); o.w = cvt(f.w);
    reinterpret_cast<ushort4*>(Wb)[i] = o;
}

// GEMM: C[t][h] = sum_e A[t][e]*Wb[h][e] + bias[h]
// Block tile 128x128, full K=256 staged once in LDS (64KB A + 64KB B).
// global_load_lds width=16, linear LDS dest, XOR-swizzled (slot ^= row&31)
// global SOURCE; same XOR on the ds_read side (rule #21 both-sides swizzle).
// 4 waves (2x2), wave tile 64x64, mfma_f32_32x32x16_bf16.
__global__ __launch_bounds__(256) void gemm_kernel(const ushort_t* __restrict__ A,
                                                   const ushort_t* __restrict__ Wb,
                                                   const float* __restrict__ bias,
                                                   float* __restrict__ out) {
    __shared__ ushort_t Abuf[128 * 256];  // 64KB, row stride 512B = 32 slots of 16B
    __shared__ ushort_t Bbuf[128 * 256];  // 64KB

    // XCD-aware bijective swizzle: 1024 blocks, 1024%8==0
    const int bid0 = blockIdx.x;
    const int bid = (bid0 & 7) * 128 + (bid0 >> 3);
    const int bn = bid & 7;        // consecutive bids share the A panel
    const int bm = bid >> 3;
    const int tid = (int)threadIdx.x;
    const int w = tid >> 6;
    const int lane = tid & 63;
    const int lrow = lane & 31;
    const int lh = lane >> 5;

    const int mbase = bm * 128;
    const int nbase = bn * 128;

    // ---- staging: 64 A-tiles + 64 B-tiles of 1KB (2 rows each), 16 per wave ----
    {
        char* Ab = (char*)Abuf;
        char* Bb = (char*)Bbuf;
#pragma unroll
        for (int j = 0; j < 16; ++j) {
            const int t = j * 4 + w;
            const int r = 2 * t + (lane >> 5);
            const int cs = (lane & 31) ^ (r & 31);  // swizzled source slot
            STAGE16(A  + (size_t)(mbase + r) * EMB + cs * 8, Ab + t * 1024);
            STAGE16(Wb + (size_t)(nbase + r) * EMB + cs * 8, Bb + t * 1024);
        }
    }
    __syncthreads();

    // ---- compute: wave tile 64x64 at (w>>1, w&1) ----
    const int m0w = (w >> 1) * 64;
    const int n0w = (w & 1) * 64;
    const int rA0 = m0w + lrow, rA1 = m0w + 32 + lrow;
    const int rB0 = n0w + lrow, rB1 = n0w + 32 + lrow;
    // all four rows have (&31)==lrow, so swizzled slot = c ^ lrow

    f32x16 acc00 = {}, acc01 = {}, acc10 = {}, acc11 = {};
#pragma unroll
    for (int ks = 0; ks < 16; ++ks) {
        const int c = ks * 2 + lh;          // 16B slot index (k = ks*16+lh*8)
        const int sl = (c ^ lrow) * 8;      // element offset within row
        bf16x8 av0 = *reinterpret_cast<const bf16x8*>(&Abuf[rA0 * EMB + sl]);
        bf16x8 av1 = *reinterpret_cast<const bf16x8*>(&Abuf[rA1 * EMB + sl]);
        bf16x8 bv0 = *reinterpret_cast<const bf16x8*>(&Bbuf[rB0 * EMB + sl]);
        bf16x8 bv1 = *reinterpret_cast<const bf16x8*>(&Bbuf[rB1 * EMB + sl]);
        acc00 = __builtin_amdgcn_mfma_f32_32x32x16_bf16(av0, bv0, acc00, 0, 0, 0);
        acc01 = __builtin_amdgcn_mfma_f32_32x32x16_bf16(av0, bv1, acc01, 0, 0, 0);
        acc10 = __builtin_amdgcn_mfma_f32_32x32x16_bf16(av1, bv0, acc10, 0, 0, 0);
        acc11 = __builtin_amdgcn_mfma_f32_32x32x16_bf16(av1, bv1, acc11, 0, 0, 0);
    }

    const int n0 = nbase + n0w;
    const int m0 = mbase + m0w;
    const float bj0 = bias[n0 + lrow];
    const float bj1 = bias[n0 + 32 + lrow];
#pragma unroll
    for (int r = 0; r < 16; ++r) {
        const int rowl = (r & 3) + 8 * (r >> 2) + 4 * lh;  // verified C/D layout
        const size_t off0 = (size_t)(m0 + rowl) * HID;
        const size_t off1 = (size_t)(m0 + 32 + rowl) * HID;
        out[off0 + n0 + lrow]      = acc00[r] + bj0;
        out[off0 + n0 + 32 + lrow] = acc01[r] + bj1;
        out[off1 + n0 + lrow]      = acc10[r] + bj0;
        out[off1 + n0 + 32 + lrow] = acc11[r] + bj1;
    }
}

extern "C" void kernel_launch(void* const* d_in, const int* in_sizes, int n_in,
                              void* d_out, int out_size, void* d_ws, size_t ws_size,
                              hipStream_t stream) {
    const uint32_t* ids32 = (const uint32_t*)d_in[0];
    const float* W = (const float*)d_in[1];
    const float* bias = (const float*)d_in[2];
    float* out = (float*)d_out;

    ushort_t* A = (ushort_t*)((char*)d_ws + WS_A_OFF);
    ushort_t* Wb = (ushort_t*)((char*)d_ws + WS_W_OFF);
    uint32_t* flag = (uint32_t*)((char*)d_ws + WS_F_OFF);

    detect_kernel<<<1, 256, 0, stream>>>(ids32, flag);
    wconv_kernel<<<(HID * EMB / 4) / 256, 256, 0, stream>>>(W, Wb);
    hash_fill_kernel<<<NTOK / 64, 64, 0, stream>>>(ids32, flag, A);
    gemm_kernel<<<(NTOK / 128) * (HID / 128), 256, 0, stream>>>(A, Wb, bias, out);
}

// Round 3
// 46.875 us; speedup vs baseline: 1.4900x; 1.0197x over previous
//
#include <hip/hip_runtime.h>
#include <stdint.h>

typedef short bf16x8 __attribute__((ext_vector_type(8)));
typedef float f32x16 __attribute__((ext_vector_type(16)));
typedef unsigned short ushort_t;

#define NTOK 16384   // 32*512
#define EMB 256
#define HID 1024
#define AH  128      // K elements per staging phase

// ---------------- ws layout ----------------
#define WS_A_OFF   0
#define WS_W_OFF   (8u * 1024u * 1024u)
#define WS_F_OFF   (WS_W_OFF + 512u * 1024u)

__device__ __forceinline__ uint32_t rotr32(uint32_t x, int n) {
    return (x >> n) | (x << (32 - n));
}

#define STAGE16(gsrc, ldsdst)                                                        \
    __builtin_amdgcn_global_load_lds(                                                \
        (const __attribute__((address_space(1))) void*)(gsrc),                       \
        (__attribute__((address_space(3))) void*)(ldsdst), 16, 0, 0)

// Detect int32 vs int64 layout of input_ids. Reads only the guaranteed 64KB
// (as uint4); if int64 little-endian, words 1,3 of every uint4 are zero.
__global__ __launch_bounds__(64) void detect_kernel(const uint4* __restrict__ ids4,
                                                    uint32_t* __restrict__ flag) {
    uint32_t acc = 0;
    for (int i = threadIdx.x; i < 4096; i += 64) {
        uint4 v = ids4[i];
        acc |= v.y | v.w;
    }
    unsigned long long m = __ballot(acc != 0);
    if (threadIdx.x == 0) *flag = (m == 0ull) ? 1u : 0u;
}

// Per token: SHA-256 + SHA-224 first-digest-byte -> bf16 A-row.
// Fused: W fp32->bf16 conversion (loads issued first, stored last; SHA hides
// the global-load latency).
__global__ __launch_bounds__(64) void hash_fill_kernel(const uint32_t* __restrict__ ids32,
                                                       const uint32_t* __restrict__ flag,
                                                       ushort_t* __restrict__ A,
                                                       const float* __restrict__ W,
                                                       ushort_t* __restrict__ Wb) {
    const int t = blockIdx.x * 64 + threadIdx.x;

    // ---- issue W-conversion loads early (4 float4 per thread) ----
    float4 wf0 = reinterpret_cast<const float4*>(W)[t];
    float4 wf1 = reinterpret_cast<const float4*>(W)[t + 16384];
    float4 wf2 = reinterpret_cast<const float4*>(W)[t + 32768];
    float4 wf3 = reinterpret_cast<const float4*>(W)[t + 49152];

    const uint32_t is64 = *flag;
    const uint32_t v = is64 ? ids32[2 * t] : ids32[t];

    const uint32_t nd = v >= 10000u ? 5u : v >= 1000u ? 4u : v >= 100u ? 3u
                         : v >= 10u ? 2u : 1u;
    uint64_t be = 0;
    uint32_t tmp = v;
    for (int j = (int)nd - 1; j >= 0; --j) {
        be |= (uint64_t)('0' + (tmp % 10u)) << (56 - 8 * j);
        tmp /= 10u;
    }
    be |= (uint64_t)0x80u << (56 - 8 * (int)nd);

    uint32_t w[16];
    w[0] = (uint32_t)(be >> 32);
    w[1] = (uint32_t)be;
#pragma unroll
    for (int i = 2; i < 15; ++i) w[i] = 0;
    w[15] = nd * 8u;

    const uint32_t K[64] = {
        0x428a2f98u,0x71374491u,0xb5c0fbcfu,0xe9b5dba5u,0x3956c25bu,0x59f111f1u,0x923f82a4u,0xab1c5ed5u,
        0xd807aa98u,0x12835b01u,0x243185beu,0x550c7dc3u,0x72be5d74u,0x80deb1feu,0x9bdc06a7u,0xc19bf174u,
        0xe49b69c1u,0xefbe4786u,0x0fc19dc6u,0x240ca1ccu,0x2de92c6fu,0x4a7484aau,0x5cb0a9dcu,0x76f988dau,
        0x983e5152u,0xa831c66du,0xb00327c8u,0xbf597fc7u,0xc6e00bf3u,0xd5a79147u,0x06ca6351u,0x14292967u,
        0x27b70a85u,0x2e1b2138u,0x4d2c6dfcu,0x53380d13u,0x650a7354u,0x766a0abbu,0x81c2c92eu,0x92722c85u,
        0xa2bfe8a1u,0xa81a664bu,0xc24b8b70u,0xc76c51a3u,0xd192e819u,0xd6990624u,0xf40e3585u,0x106aa070u,
        0x19a4c116u,0x1e376c08u,0x2748774cu,0x34b0bcb5u,0x391c0cb3u,0x4ed8aa4au,0x5b9cca4fu,0x682e6ff3u,
        0x748f82eeu,0x78a5636fu,0x84c87814u,0x8cc70208u,0x90befffau,0xa4506cebu,0xbef9a3f7u,0xc67178f2u};

    uint32_t a0=0x6a09e667u,b0=0xbb67ae85u,c0=0x3c6ef372u,d0=0xa54ff53au,
             e0=0x510e527fu,f0=0x9b05688cu,g0=0x1f83d9abu,h0=0x5be0cd19u;
    uint32_t a1=0xc1059ed8u,b1=0x367cd507u,c1=0x3070dd17u,d1=0xf70e5939u,
             e1=0xffc00b31u,f1=0x68581511u,g1=0x64f98fa7u,h1=0xbefa4fa4u;

#pragma unroll
    for (int tt = 0; tt < 64; ++tt) {
        uint32_t wt;
        if (tt < 16) {
            wt = w[tt];
        } else {
            uint32_t w2 = w[(tt - 2) & 15], w7 = w[(tt - 7) & 15];
            uint32_t w15 = w[(tt - 15) & 15], w16 = w[tt & 15];
            uint32_t s0 = rotr32(w15, 7) ^ rotr32(w15, 18) ^ (w15 >> 3);
            uint32_t s1 = rotr32(w2, 17) ^ rotr32(w2, 19) ^ (w2 >> 10);
            wt = w16 + s0 + w7 + s1;
            w[tt & 15] = wt;
        }
        const uint32_t kw = K[tt] + wt;
        {
            uint32_t S1 = rotr32(e0, 6) ^ rotr32(e0, 11) ^ rotr32(e0, 25);
            uint32_t ch = (e0 & f0) ^ (~e0 & g0);
            uint32_t T1 = h0 + S1 + ch + kw;
            uint32_t S0 = rotr32(a0, 2) ^ rotr32(a0, 13) ^ rotr32(a0, 22);
            uint32_t mj = (a0 & b0) ^ (a0 & c0) ^ (b0 & c0);
            uint32_t T2 = S0 + mj;
            h0 = g0; g0 = f0; f0 = e0; e0 = d0 + T1;
            d0 = c0; c0 = b0; b0 = a0; a0 = T1 + T2;
        }
        {
            uint32_t S1 = rotr32(e1, 6) ^ rotr32(e1, 11) ^ rotr32(e1, 25);
            uint32_t ch = (e1 & f1) ^ (~e1 & g1);
            uint32_t T1 = h1 + S1 + ch + kw;
            uint32_t S0 = rotr32(a1, 2) ^ rotr32(a1, 13) ^ rotr32(a1, 22);
            uint32_t mj = (a1 & b1) ^ (a1 & c1) ^ (b1 & c1);
            uint32_t T2 = S0 + mj;
            h1 = g1; g1 = f1; f1 = e1; e1 = d1 + T1;
            d1 = c1; c1 = b1; b1 = a1; a1 = T1 + T2;
        }
    }
    const uint32_t hv1 = ((0x6a09e667u + a0) >> 24) & 0xFFu;  // sha256 digest[0]
    const uint32_t hv2 = ((0xc1059ed8u + a1) >> 24) & 0xFFu;  // sha224 digest[0]

    ushort_t* row = A + (size_t)t * EMB;
#pragma unroll
    for (int k0 = 0; k0 < EMB; k0 += 8) {
        bf16x8 pack;
#pragma unroll
        for (int e = 0; e < 8; ++e) {
            uint32_t val = (hv1 + (uint32_t)(k0 + e) * hv2) & 255u;
            pack[e] = (short)(__float_as_uint((float)val) >> 16);  // exact
        }
        *reinterpret_cast<bf16x8*>(row + k0) = pack;
    }

    // ---- finish W conversion (RNE) ----
    auto cvt = [](float x) -> ushort_t {
        uint32_t b = __float_as_uint(x);
        return (ushort_t)((b + 0x7FFFu + ((b >> 16) & 1u)) >> 16);
    };
    auto cvt4 = [&](float4 f) -> ushort4 {
        ushort4 o; o.x = cvt(f.x); o.y = cvt(f.y); o.z = cvt(f.z); o.w = cvt(f.w);
        return o;
    };
    reinterpret_cast<ushort4*>(Wb)[t]         = cvt4(wf0);
    reinterpret_cast<ushort4*>(Wb)[t + 16384] = cvt4(wf1);
    reinterpret_cast<ushort4*>(Wb)[t + 32768] = cvt4(wf2);
    reinterpret_cast<ushort4*>(Wb)[t + 49152] = cvt4(wf3);
}

// GEMM: C[t][h] = sum_e A[t][e]*Wb[h][e] + bias[h]
// Block tile 128x128; K=256 staged in TWO 64KB phases (A 32KB + B 32KB each)
// -> LDS 64KB -> 2 blocks/CU so one block's staging overlaps the other's
// MFMA+stores. Row = AH(128) elems = 16 slots of 16B; both-sides XOR swizzle
// slot ^= (row&15). 4 waves (2x2), wave tile 64x64, mfma_f32_32x32x16_bf16.
__global__ __launch_bounds__(256, 2) void gemm_kernel(const ushort_t* __restrict__ A,
                                                      const ushort_t* __restrict__ Wb,
                                                      const float* __restrict__ bias,
                                                      float* __restrict__ out) {
    __shared__ ushort_t Abuf[128 * AH];  // 32KB
    __shared__ ushort_t Bbuf[128 * AH];  // 32KB

    // XCD-aware bijective swizzle: 1024 blocks, 1024%8==0
    const int bid0 = blockIdx.x;
    const int bid = (bid0 & 7) * 128 + (bid0 >> 3);
    const int bn = bid & 7;
    const int bm = bid >> 3;
    const int tid = (int)threadIdx.x;
    const int w = tid >> 6;
    const int lane = tid & 63;
    const int lrow = lane & 31;
    const int lh = lane >> 5;

    const int mbase = bm * 128;
    const int nbase = bn * 128;

    const int dr = lane >> 4;   // staging: row within the 4-row/1KB group
    const int ds = lane & 15;   // staging: dest slot
    const int sx = lrow & 15;   // read-side XOR key (row&15 for all our rows)

    const int m0w = (w >> 1) * 64;
    const int n0w = (w & 1) * 64;
    const int rA0 = m0w + lrow, rA1 = m0w + 32 + lrow;
    const int rB0 = n0w + lrow, rB1 = n0w + 32 + lrow;

    f32x16 acc00 = {}, acc01 = {}, acc10 = {}, acc11 = {};

    for (int ph = 0; ph < 2; ++ph) {
        // ---- stage one K-half: 32 x 1KB tiles each for A and B, 8 per wave ----
        {
            char* Ab = (char*)Abuf;
            char* Bb = (char*)Bbuf;
            const int kofs = ph * AH;
#pragma unroll
            for (int j = 0; j < 8; ++j) {
                const int tt = j * 4 + w;
                const int r = 4 * tt + dr;
                const int cs = ds ^ (r & 15);  // pre-swizzled source slot
                STAGE16(A  + (size_t)(mbase + r) * EMB + kofs + cs * 8, Ab + tt * 1024);
                STAGE16(Wb + (size_t)(nbase + r) * EMB + kofs + cs * 8, Bb + tt * 1024);
            }
        }
        __syncthreads();

        // ---- compute this K-half ----
#pragma unroll
        for (int ks = 0; ks < 8; ++ks) {
            const int c = ks * 2 + lh;        // 16B slot in row
            const int sl = (c ^ sx) * 8;      // swizzled element offset
            bf16x8 av0 = *reinterpret_cast<const bf16x8*>(&Abuf[rA0 * AH + sl]);
            bf16x8 av1 = *reinterpret_cast<const bf16x8*>(&Abuf[rA1 * AH + sl]);
            bf16x8 bv0 = *reinterpret_cast<const bf16x8*>(&Bbuf[rB0 * AH + sl]);
            bf16x8 bv1 = *reinterpret_cast<const bf16x8*>(&Bbuf[rB1 * AH + sl]);
            acc00 = __builtin_amdgcn_mfma_f32_32x32x16_bf16(av0, bv0, acc00, 0, 0, 0);
            acc01 = __builtin_amdgcn_mfma_f32_32x32x16_bf16(av0, bv1, acc01, 0, 0, 0);
            acc10 = __builtin_amdgcn_mfma_f32_32x32x16_bf16(av1, bv0, acc10, 0, 0, 0);
            acc11 = __builtin_amdgcn_mfma_f32_32x32x16_bf16(av1, bv1, acc11, 0, 0, 0);
        }
        __syncthreads();  // all reads done before next phase overwrites
    }

    const int n0 = nbase + n0w;
    const int m0 = mbase + m0w;
    const float bj0 = bias[n0 + lrow];
    const float bj1 = bias[n0 + 32 + lrow];
#pragma unroll
    for (int r = 0; r < 16; ++r) {
        const int rowl = (r & 3) + 8 * (r >> 2) + 4 * lh;  // verified C/D layout
        const size_t off0 = (size_t)(m0 + rowl) * HID;
        const size_t off1 = (size_t)(m0 + 32 + rowl) * HID;
        out[off0 + n0 + lrow]      = acc00[r] + bj0;
        out[off0 + n0 + 32 + lrow] = acc01[r] + bj1;
        out[off1 + n0 + lrow]      = acc10[r] + bj0;
        out[off1 + n0 + 32 + lrow] = acc11[r] + bj1;
    }
}

extern "C" void kernel_launch(void* const* d_in, const int* in_sizes, int n_in,
                              void* d_out, int out_size, void* d_ws, size_t ws_size,
                              hipStream_t stream) {
    const uint32_t* ids32 = (const uint32_t*)d_in[0];
    const float* W = (const float*)d_in[1];
    const float* bias = (const float*)d_in[2];
    float* out = (float*)d_out;

    ushort_t* A = (ushort_t*)((char*)d_ws + WS_A_OFF);
    ushort_t* Wb = (ushort_t*)((char*)d_ws + WS_W_OFF);
    uint32_t* flag = (uint32_t*)((char*)d_ws + WS_F_OFF);

    detect_kernel<<<1, 64, 0, stream>>>((const uint4*)ids32, flag);
    hash_fill_kernel<<<NTOK / 64, 64, 0, stream>>>(ids32, flag, A, W, Wb);
    gemm_kernel<<<(NTOK / 128) * (HID / 128), 256, 0, stream>>>(A, Wb, bias, out);
}